// Round 4
// baseline (225.439 us; speedup 1.0000x reference)
//
#include <hip/hip_runtime.h>
#include <cstdint>
#include <cstddef>

#define EPS 1e-8f

// Fixed problem instance
#define Bsz 8
#define Nn  5
#define Kk  5
#define Ll  128
#define Ff  768
#define Tt  11                 // 2N+1
#define KL  640                // K*L
#define ROWS_PER_B 2560        // N*Q*L
#define NROWS 20480
#define F4  192                // Ff/4
#define BN  40                 // B*N

// ---- stage1 geometry: 16 rows per block, partials to ws (no f-atomics) ----
#define S1_ROWS 16
#define S1_CH   (KL / S1_ROWS)     // 40 chunks per bn
#define S1_NBLK (BN * S1_CH)       // 1600 blocks
#define PART_STRIDE (3 * Ff)       // 2304 floats per partial record
#define PART_STRIDE4 (PART_STRIDE / 4)  // 576 float4

// ---------------- Stage 1: masked partial sums ----------------
// 1600 blocks x 192 threads (3 waves). Lane owns one float4 column; loops 16 rows.
// Fully coalesced 16 B/lane loads; partials written coalesced; only cnt uses atomics.
__global__ __launch_bounds__(192) void stage1(
    const float* __restrict__ sup,      // [B][N][K][L][F]
    const int*   __restrict__ Bm,       // [B][N][K][L]
    const int*   __restrict__ Im,
    float* __restrict__ part,           // [S1_NBLK][3][Ff]
    float* __restrict__ cnt)            // [BN][2] (zeroed)
{
    int blk = blockIdx.x;
    int bn  = blk / S1_CH;
    int ch  = blk - bn * S1_CH;
    int tid = threadIdx.x;

    const float4* sp = (const float4*)(sup + ((size_t)bn * KL + ch * S1_ROWS) * Ff);
    const int*    bp = Bm + bn * KL + ch * S1_ROWS;
    const int*    ip = Im + bn * KL + ch * S1_ROWS;

    __shared__ float smB[S1_ROWS];
    __shared__ float smI[S1_ROWS];
    if (tid < S1_ROWS) {
        smB[tid] = (float)bp[tid];
        smI[tid] = (float)ip[tid];
    }
    __syncthreads();

    float4 aB = {0,0,0,0}, aI = {0,0,0,0}, aO = {0,0,0,0};
    #pragma unroll 8
    for (int p = 0; p < S1_ROWS; ++p) {
        float4 v = sp[tid + p * F4];
        float mb = smB[p], mi = smI[p];
        float mo = 1.0f - mb - mi;
        aB.x = fmaf(mb, v.x, aB.x); aB.y = fmaf(mb, v.y, aB.y);
        aB.z = fmaf(mb, v.z, aB.z); aB.w = fmaf(mb, v.w, aB.w);
        aI.x = fmaf(mi, v.x, aI.x); aI.y = fmaf(mi, v.y, aI.y);
        aI.z = fmaf(mi, v.z, aI.z); aI.w = fmaf(mi, v.w, aI.w);
        aO.x = fmaf(mo, v.x, aO.x); aO.y = fmaf(mo, v.y, aO.y);
        aO.z = fmaf(mo, v.z, aO.z); aO.w = fmaf(mo, v.w, aO.w);
    }
    float4* o = (float4*)(part + (size_t)blk * PART_STRIDE);
    o[tid]          = aB;
    o[F4 + tid]     = aI;
    o[2 * F4 + tid] = aO;

    if (tid == 0) { float s = 0; for (int p = 0; p < S1_ROWS; ++p) s += smB[p]; atomicAdd(&cnt[2*bn],   s); }
    if (tid == 1) { float s = 0; for (int p = 0; p < S1_ROWS; ++p) s += smI[p]; atomicAdd(&cnt[2*bn+1], s); }
}

// ---------------- Stage 2: reduce partials -> prototypes ----------------
// 66 blocks x 256 threads. Threads [0,15360): (bn, set in {B,I}, f4) — 40 float4
// reads at stride 2304. Threads [15360,16896): (b, f4) for the O prototype.
__global__ __launch_bounds__(256) void stage2(
    const float* __restrict__ part,
    const float* __restrict__ cnt,
    float* __restrict__ proto)          // [B][Tt][Ff]
{
    int gid = blockIdx.x * 256 + threadIdx.x;
    float4* protoP4 = (float4*)proto;

    if (gid < BN * 2 * F4) {
        int bn  = gid / (2 * F4);
        int r   = gid - bn * 2 * F4;
        int set = r / F4;
        int f4  = r - set * F4;
        const float4* src = (const float4*)(part + (size_t)bn * S1_CH * PART_STRIDE + set * Ff) + f4;
        float4 s = {0,0,0,0};
        #pragma unroll 8
        for (int c = 0; c < S1_CH; ++c) {
            float4 v = src[(size_t)c * PART_STRIDE4];
            s.x += v.x; s.y += v.y; s.z += v.z; s.w += v.w;
        }
        float sc = 1.0f / (cnt[2 * bn + set] + EPS);
        int b = bn / Nn, n = bn - b * Nn;
        int tag = 1 + 2 * n + set;
        float4 o = { s.x * sc, s.y * sc, s.z * sc, s.w * sc };
        protoP4[((size_t)b * Tt + tag) * F4 + f4] = o;
    } else if (gid < BN * 2 * F4 + Bsz * F4) {
        int idx = gid - BN * 2 * F4;
        int b   = idx / F4;
        int f4  = idx - b * F4;
        float4 s = {0,0,0,0};
        float cO = (float)(KL * Nn);
        for (int n = 0; n < Nn; ++n) {
            int bn = b * Nn + n;
            const float4* src = (const float4*)(part + (size_t)bn * S1_CH * PART_STRIDE + 2 * Ff) + f4;
            #pragma unroll 8
            for (int c = 0; c < S1_CH; ++c) {
                float4 v = src[(size_t)c * PART_STRIDE4];
                s.x += v.x; s.y += v.y; s.z += v.z; s.w += v.w;
            }
            cO -= cnt[2 * bn] + cnt[2 * bn + 1];
        }
        float sc = 1.0f / (cO + EPS);
        float4 o = { s.x * sc, s.y * sc, s.z * sc, s.w * sc };
        protoP4[(size_t)b * Tt * F4 + f4] = o;
    }
}

// ---------------- Stage 3: logits + argmax + log-softmax NLL ----------------
// 320 blocks x 128 threads (2 waves). Block covers 64 rows. Thread = 2 rows x
// quarter-row (48 float4). Lane = 4*p + s: p = row-pair, s = f-slice.
// Proto in LDS, slice-padded ([t][s][49]) so the 4 concurrent broadcast
// addresses land in disjoint bank quads. acc[22] stays in registers (no spill).
// Reduction over s: 2 shuffles per accumulator (xor 1, xor 2).
#define S3_ROWS 64
#define S3_NBLK (NROWS / S3_ROWS)   // 320
#define BLKS_PER_B (ROWS_PER_B / S3_ROWS)  // 40

__global__ __launch_bounds__(128) void stage3(
    const float* __restrict__ query,    // [B][2560][Ff]
    const float* __restrict__ proto,    // [B][Tt][Ff]
    const int*   __restrict__ label,    // [NROWS]
    float* __restrict__ out_logits,     // [NROWS][Tt]
    float* __restrict__ out_pred,       // [NROWS]
    float* __restrict__ loss_out)       // [1]
{
    __shared__ float4 ldsP[Tt * 4 * 49];   // 34,496 B

    int blk = blockIdx.x;
    int b   = blk / BLKS_PER_B;

    // Stage proto for this batch into LDS (coalesced global reads).
    const float4* pg = (const float4*)(proto + (size_t)b * Tt * Ff);
    for (int idx = threadIdx.x; idx < Tt * F4; idx += 128) {
        int t  = idx / F4;
        int f4 = idx - t * F4;
        int s  = f4 / 48;
        int j  = f4 - 48 * s;
        ldsP[(t * 4 + s) * 49 + j] = pg[idx];
    }
    __syncthreads();

    int w    = threadIdx.x >> 6;
    int lane = threadIdx.x & 63;
    int p    = lane >> 2;
    int s    = lane & 3;

    size_t row0 = (size_t)blk * S3_ROWS + w * 32 + p * 2;   // global row of even row
    const float4* q0 = (const float4*)(query + row0 * Ff) + s * 48;
    const float4* q1 = q0 + F4;   // odd row (row0+1), same slice

    float a0[Tt], a1[Tt];
    #pragma unroll
    for (int t = 0; t < Tt; ++t) { a0[t] = 0.0f; a1[t] = 0.0f; }

    const float4* pb = &ldsP[s * 49];
    #pragma unroll 2
    for (int j = 0; j < 48; ++j) {
        float4 u = q0[j];
        float4 v = q1[j];
        #pragma unroll
        for (int t = 0; t < Tt; ++t) {
            float4 pv = pb[t * (4 * 49) + j];
            float d0 = a0[t], d1 = a1[t];
            d0 = fmaf(u.x, pv.x, d0); d0 = fmaf(u.y, pv.y, d0);
            d0 = fmaf(u.z, pv.z, d0); d0 = fmaf(u.w, pv.w, d0);
            d1 = fmaf(v.x, pv.x, d1); d1 = fmaf(v.y, pv.y, d1);
            d1 = fmaf(v.z, pv.z, d1); d1 = fmaf(v.w, pv.w, d1);
            a0[t] = d0; a1[t] = d1;
        }
    }

    // Combine the 4 f-slices (lanes 4p..4p+3) — 2 shuffle levels.
    #pragma unroll
    for (int t = 0; t < Tt; ++t) {
        a0[t] += __shfl_xor(a0[t], 1, 64); a0[t] += __shfl_xor(a0[t], 2, 64);
        a1[t] += __shfl_xor(a1[t], 1, 64); a1[t] += __shfl_xor(a1[t], 2, 64);
    }

    float wloss = 0.0f;
    if (s == 0) {
        // Epilogue for both rows (lane holds full 11-logit rows).
        #pragma unroll
        for (int rr = 0; rr < 2; ++rr) {
            size_t grow = row0 + rr;
            float* a = rr ? a1 : a0;
            float m = a[0]; int bt = 0;
            #pragma unroll
            for (int t = 1; t < Tt; ++t) if (a[t] > m) { m = a[t]; bt = t; }  // first-max
            float sum = 0.0f;
            #pragma unroll
            for (int t = 0; t < Tt; ++t) sum += __expf(a[t] - m);
            int lab = label[grow];
            float labv = a[0];
            #pragma unroll
            for (int t = 1; t < Tt; ++t) labv = (lab == t) ? a[t] : labv;
            #pragma unroll
            for (int t = 0; t < Tt; ++t) out_logits[grow * Tt + t] = a[t];
            out_pred[grow] = (float)bt;
            wloss += (m + __logf(sum)) - labv;
        }
    }
    // Wave-level loss reduction, one atomic per wave.
    #pragma unroll
    for (int off = 32; off > 0; off >>= 1) wloss += __shfl_xor(wloss, off, 64);
    if (lane == 0) atomicAdd(loss_out, wloss * (1.0f / (float)NROWS));
}

// ---------------- Host launch ----------------
extern "C" void kernel_launch(void* const* d_in, const int* in_sizes, int n_in,
                              void* d_out, int out_size, void* d_ws, size_t ws_size,
                              hipStream_t stream) {
    const float* sup   = (const float*)d_in[0];
    const float* query = (const float*)d_in[1];
    const int*   Bm    = (const int*)d_in[2];
    const int*   Im    = (const int*)d_in[3];
    const int*   lab   = (const int*)d_in[4];

    // ws layout: part [1600][2304] | cnt [40][2] | proto [8][11][768]
    float* w     = (float*)d_ws;
    float* part  = w;
    float* cnt   = part + (size_t)S1_NBLK * PART_STRIDE;   // +3,686,400
    float* proto = cnt + 2 * BN;                           // +80 (16B-aligned)

    float* loss_out   = (float*)d_out;
    float* out_logits = (float*)d_out + 1;
    float* out_pred   = (float*)d_out + 1 + (size_t)NROWS * Tt;

    hipMemsetAsync(cnt, 0, 2 * BN * sizeof(float), stream);
    hipMemsetAsync(d_out, 0, sizeof(float), stream);

    stage1<<<S1_NBLK, 192, 0, stream>>>(sup, Bm, Im, part, cnt);
    stage2<<<66, 256, 0, stream>>>(part, cnt, proto);
    stage3<<<S3_NBLK, 128, 0, stream>>>(query, proto, lab, out_logits, out_pred, loss_out);
}